// Round 1
// baseline (150.046 us; speedup 1.0000x reference)
//
#include <hip/hip_runtime.h>

// Differentiable gaussian renderer, separable-splat formulation.
//
//   w(px,py) = op * exp(-0.5*((px-u)^2+(py-v)^2)/var)
//            = [exp2(ke*(py-v)^2)] * [exp2(ke*(px-u)^2)],  ke = -0.5*log2(e)/var
//
// => per pose: C[y][n] = sum_g A[y][g] * B[g][n],  n = c*128+x
//    A[y][g]          = fy_g(y)                    (shared across channels)
//    B[g][c*128+x]    = (op*color_c)_g * fx_g(x)   (c=3: color=1 -> denominator)
// GEMM: M=128, N=512, K=65536 per pose (17.2 GFLOP bf16 total) + 33.5M exp2.
//
// Fused kernel: 256 blocks (2 poses x 128 K-splits, 1/CU), 1024 thr = 16 waves,
// wave tile [32y x 128n], mfma_f32_16x16x32_bf16 (HW-verified fragment layouts).
// Each block stages its 512-gaussian slab params once, then loops 8 chunks of
// 64 gaussians: build bf16 A/B tiles in LDS (exp2 + pack) -> MFMA -> next.
// Epilogue: fp32 atomicAdd into 512KB accumulator in d_ws (L2-resident).
// normalize kernel: img = num/(den + 16*1e-8), tile-transposed output layout.

#define H_IMG 128
#define W_IMG 128
#define FX_C 120.0f
#define FY_C 120.0f
#define CX_C 64.0f
#define CY_C 64.0f
#define NG 65536
#define SLAB 512          // gaussians per block
#define KSPLIT 128        // NG / SLAB
#define KC 64             // gaussians per LDS chunk
#define NCHUNK 8          // SLAB / KC
#define APAD 72           // 64 + 8 bf16 pad: row stride 144B (16B aligned, breaks bank conflicts)
#define NEG_HALF_LOG2E -0.72134752044448170f
#define EPS_TOT 1.6e-7f   // n_chunks(16) * 1e-8

typedef __attribute__((ext_vector_type(8))) short short8;   // 8 bf16 = 4 VGPRs
typedef __attribute__((ext_vector_type(4))) float f32x4;    // MFMA acc

// round-to-nearest-even f32 -> bf16, pack two into a uint (a=low, b=high)
__device__ __forceinline__ unsigned bfpk(float a, float b) {
    unsigned ua = __float_as_uint(a), ub = __float_as_uint(b);
    ua = (ua + 0x7FFFu + ((ua >> 16) & 1u)) >> 16;
    ub = (ub + 0x7FFFu + ((ub >> 16) & 1u)) & 0xFFFF0000u;
    return ua | ub;
}

__global__ void zero_accum_kernel(float* __restrict__ p) {
    p[blockIdx.x * 256 + threadIdx.x] = 0.0f;   // grid 512 x 256 = 131072 floats
}

__global__ __launch_bounds__(1024) void render_accum_kernel(
    const float* __restrict__ gpos, const float* __restrict__ gcol,
    const float* __restrict__ gopa, const float* __restrict__ gscl,
    const float* __restrict__ qvec, const float* __restrict__ tvec,
    float* __restrict__ accum)                       // [2][128 y][512 n] fp32
{
    __shared__ ushort A_lds[H_IMG][APAD];            // fy,  [y][kc]      18 KB
    __shared__ ushort B_lds[512][APAD];              // B^T, [n][kc]      72 KB
    __shared__ float u_s[SLAB], v_s[SLAB], ke_s[SLAB];
    __shared__ float wc_s[4][SLAB];                  // op*{r,g,b,1}

    const int split = blockIdx.x;                    // 0..127
    const int pose  = blockIdx.y;                    // 0..1
    const int tid   = threadIdx.x;                   // 0..1023

    // ---- camera: quaternion -> R (all threads, registers) ----
    float q0 = qvec[pose*4+0], q1 = qvec[pose*4+1], q2 = qvec[pose*4+2], q3 = qvec[pose*4+3];
    float rn = rsqrtf(q0*q0 + q1*q1 + q2*q2 + q3*q3);
    float qw = q0*rn, qx = q1*rn, qy = q2*rn, qz = q3*rn;
    float r00 = 1.0f-2.0f*(qy*qy+qz*qz), r01 = 2.0f*(qx*qy-qz*qw), r02 = 2.0f*(qx*qz+qy*qw);
    float r10 = 2.0f*(qx*qy+qz*qw), r11 = 1.0f-2.0f*(qx*qx+qz*qz), r12 = 2.0f*(qy*qz-qx*qw);
    float r20 = 2.0f*(qx*qz-qy*qw), r21 = 2.0f*(qy*qz+qx*qw), r22 = 1.0f-2.0f*(qx*qx+qy*qy);
    float tx = tvec[pose*3+0], ty = tvec[pose*3+1], tz = tvec[pose*3+2];

    // ---- per-slab gaussian params, staged once ----
    if (tid < SLAB) {
        int g = split*SLAB + tid;
        float p0 = gpos[g*3+0], p1 = gpos[g*3+1], p2 = gpos[g*3+2];
        float cxm = r00*p0 + r01*p1 + r02*p2 + tx;
        float cym = r10*p0 + r11*p1 + r12*p2 + ty;
        float czm = r20*p0 + r21*p1 + r22*p2 + tz;
        float iz  = 1.0f / czm;
        u_s[tid] = cxm*iz*FX_C + CX_C;
        v_s[tid] = cym*iz*FY_C + CY_C;
        float s  = gscl[g];
        ke_s[tid] = NEG_HALF_LOG2E / (s*s);
        float og = gopa[tid + split*SLAB];
        wc_s[0][tid] = og * gcol[g*3+0];
        wc_s[1][tid] = og * gcol[g*3+1];
        wc_s[2][tid] = og * gcol[g*3+2];
        wc_s[3][tid] = og;
    }
    __syncthreads();

    const int row_j = tid >> 3;          // 0..127: y for fy, x for fx
    const int gc0   = (tid & 7) << 3;    // 0,8,...,56: kc base (8 gaussians/thread)
    const float cj  = (float)row_j;
    const int lane  = tid & 63;
    const int wave  = tid >> 6;          // 0..15
    const int wy    = wave >> 2;         // y band: [wy*32, wy*32+32)
    const int wn    = wave & 3;          // n band: [wn*128, wn*128+128) == channel wn

    f32x4 acc0[8] = {};                  // rows wy*32 + (lane>>4)*4 + r,  +0
    f32x4 acc1[8] = {};                  //                                +16

    for (int ch = 0; ch < NCHUNK; ++ch) {
        const int gb = (ch << 6) + gc0;
        const float4 ka = *(const float4*)&ke_s[gb];
        const float4 kb = *(const float4*)&ke_s[gb+4];
        // ---- stage fy -> A_lds[row_j][gc0..gc0+7] ----
        {
            const float4 va = *(const float4*)&v_s[gb];
            const float4 vb = *(const float4*)&v_s[gb+4];
            float d, f0,f1,f2,f3,f4,f5,f6,f7;
            d = cj - va.x; f0 = exp2f(ka.x*d*d);
            d = cj - va.y; f1 = exp2f(ka.y*d*d);
            d = cj - va.z; f2 = exp2f(ka.z*d*d);
            d = cj - va.w; f3 = exp2f(ka.w*d*d);
            d = cj - vb.x; f4 = exp2f(kb.x*d*d);
            d = cj - vb.y; f5 = exp2f(kb.y*d*d);
            d = cj - vb.z; f6 = exp2f(kb.z*d*d);
            d = cj - vb.w; f7 = exp2f(kb.w*d*d);
            uint4 pk;
            pk.x = bfpk(f0,f1); pk.y = bfpk(f2,f3);
            pk.z = bfpk(f4,f5); pk.w = bfpk(f6,f7);
            *(uint4*)&A_lds[row_j][gc0] = pk;
        }
        // ---- stage fx, channel-weighted -> B_lds[c*128 + row_j][gc0..] ----
        {
            const float4 ua = *(const float4*)&u_s[gb];
            const float4 ub = *(const float4*)&u_s[gb+4];
            float d, x0,x1,x2,x3,x4,x5,x6,x7;
            d = cj - ua.x; x0 = exp2f(ka.x*d*d);
            d = cj - ua.y; x1 = exp2f(ka.y*d*d);
            d = cj - ua.z; x2 = exp2f(ka.z*d*d);
            d = cj - ua.w; x3 = exp2f(ka.w*d*d);
            d = cj - ub.x; x4 = exp2f(kb.x*d*d);
            d = cj - ub.y; x5 = exp2f(kb.y*d*d);
            d = cj - ub.z; x6 = exp2f(kb.z*d*d);
            d = cj - ub.w; x7 = exp2f(kb.w*d*d);
            #pragma unroll
            for (int c = 0; c < 4; ++c) {
                const float4 wa = *(const float4*)&wc_s[c][gb];
                const float4 wb = *(const float4*)&wc_s[c][gb+4];
                uint4 pk;
                pk.x = bfpk(x0*wa.x, x1*wa.y);
                pk.y = bfpk(x2*wa.z, x3*wa.w);
                pk.z = bfpk(x4*wb.x, x5*wb.y);
                pk.w = bfpk(x6*wb.z, x7*wb.w);
                *(uint4*)&B_lds[(c << 7) + row_j][gc0] = pk;
            }
        }
        __syncthreads();
        // ---- MFMA over this chunk: K=64 -> 2 k-steps of 32 ----
        {
            const int kq = (lane >> 4) << 3;           // verified: k = quad*8 + j
            #pragma unroll
            for (int ks = 0; ks < 2; ++ks) {
                const int ko = ks*32 + kq;
                short8 a0 = *(const short8*)&A_lds[wy*32      + (lane & 15)][ko];
                short8 a1 = *(const short8*)&A_lds[wy*32 + 16 + (lane & 15)][ko];
                #pragma unroll
                for (int ni = 0; ni < 8; ++ni) {
                    short8 bf = *(const short8*)&B_lds[wn*128 + ni*16 + (lane & 15)][ko];
                    acc0[ni] = __builtin_amdgcn_mfma_f32_16x16x32_bf16(a0, bf, acc0[ni], 0, 0, 0);
                    acc1[ni] = __builtin_amdgcn_mfma_f32_16x16x32_bf16(a1, bf, acc1[ni], 0, 0, 0);
                }
            }
        }
        __syncthreads();
    }

    // ---- epilogue: atomic accumulate [128 x 512] partial ----
    // C/D layout (verified): col(n) = lane&15, row(m) = (lane>>4)*4 + reg
    const int m_base = wy*32 + ((lane >> 4) << 2);
    const int n_base = wn*128 + (lane & 15);
    float* bp = accum + ((size_t)(pose*H_IMG + m_base) * 512 + n_base);
    #pragma unroll
    for (int ni = 0; ni < 8; ++ni) {
        #pragma unroll
        for (int r = 0; r < 4; ++r) {
            atomicAdd(bp + r*512        + ni*16, acc0[ni][r]);
            atomicAdd(bp + (16 + r)*512 + ni*16, acc1[ni][r]);
        }
    }
}

__global__ void normalize_kernel(const float* __restrict__ acc, float* __restrict__ out) {
    int idx = blockIdx.x * 256 + threadIdx.x;   // 0..32767 : (pose, y, x)
    int x = idx & 127;
    int y = (idx >> 7) & 127;
    int p = idx >> 14;
    const float* base = acc + (size_t)(p*128 + y) * 512;
    float inv = 1.0f / (base[384 + x] + EPS_TOT);
    // output: [pose*16 + tile][3][32][32], tile = y>>3, q = (y&7)*128 + x
    int t = y >> 3;
    int q = ((y & 7) << 7) + x;
    float* ob = out + (size_t)((p*16 + t)*3) * 1024 + q;
    ob[0]    = base[x]       * inv;
    ob[1024] = base[128 + x] * inv;
    ob[2048] = base[256 + x] * inv;
}

extern "C" void kernel_launch(void* const* d_in, const int* in_sizes, int n_in,
                              void* d_out, int out_size, void* d_ws, size_t ws_size,
                              hipStream_t stream) {
    const float* gpos = (const float*)d_in[0];   // [65536,3]
    const float* gcol = (const float*)d_in[1];   // [65536,3]
    const float* gopa = (const float*)d_in[2];   // [65536,1]
    const float* gscl = (const float*)d_in[3];   // [65536,1]
    const float* qv   = (const float*)d_in[4];   // [2,4]
    const float* tv   = (const float*)d_in[5];   // [2,3]
    float* out = (float*)d_out;                  // [32,3,32,32] fp32
    float* acc = (float*)d_ws;                   // [2][128][512] fp32 = 512 KB

    zero_accum_kernel<<<dim3(512), dim3(256), 0, stream>>>(acc);
    render_accum_kernel<<<dim3(KSPLIT, 2), dim3(1024), 0, stream>>>(
        gpos, gcol, gopa, gscl, qv, tv, acc);
    normalize_kernel<<<dim3(128), dim3(256), 0, stream>>>(acc, out);
}

// Round 3
// 117.624 us; speedup vs baseline: 1.2756x; 1.2756x over previous
//
#include <hip/hip_runtime.h>

// Differentiable gaussian renderer, separable-splat formulation.
//
//   w(px,py) = op * exp(-0.5*((px-u)^2+(py-v)^2)/var)
//            = [exp2(ke*(py-v)^2)] * [exp2(ke*(px-u)^2)],  ke = -0.5*log2(e)/var
//
// => per pose: C[y][n] = sum_g A[y][g] * B[g][n],  n = c*128+x
//    A[y][g]       = fy_g(y)                    (shared across channels)
//    B[g][c*128+x] = (op*color_c)_g * fx_g(x)   (c=3: color=1 -> denominator)
// GEMM: M=128, N=512, K=65536 per pose (17.2 GFLOP bf16) + ~50M exp2.
//
// R2 -> R3: fp16 partials failed (subnormal-range absolute quantization of
// dim pixels -> absmax 0.199). Now fp32 partials at the SAME 33.5MB budget:
// grid = 2 poses x 2 y-halves x 64 K-splits = 256 blocks, each [64y x 512n]
// fp32 partial over a 1024-gaussian slab. Staging cost recovered with raw
// v_exp_f32 (__builtin_amdgcn_exp2f) and a 3-op bf16 pair pack (v_perm_b32).
// Contention-free stores; reduce+normalize kernel sums the 64 splits.

#define H_IMG 128
#define W_IMG 128
#define FX_C 120.0f
#define FY_C 120.0f
#define CX_C 64.0f
#define CY_C 64.0f
#define NG 65536
#define SLAB 1024         // gaussians per block
#define KSPLIT 64         // NG / SLAB
#define KC 64             // gaussians per LDS chunk
#define NCHUNK 16         // SLAB / KC
#define APAD 72           // 64 + 8 bf16 pad: row stride 144B (16B aligned)
#define NEG_HALF_LOG2E -0.72134752044448170f
#define EPS_TOT 1.6e-7f   // n_chunks(16) * 1e-8

#if __has_builtin(__builtin_amdgcn_exp2f)
#define EXP2(x) __builtin_amdgcn_exp2f(x)
#else
#define EXP2(x) exp2f(x)
#endif

typedef __attribute__((ext_vector_type(8))) short short8;   // 8 bf16 = 4 VGPRs
typedef __attribute__((ext_vector_type(4))) float f32x4;    // MFMA acc

// pack two f32 -> two bf16 (round-half-up) in 3 VALU ops via v_perm_b32.
// result low16 = bf16(a), high16 = bf16(b). Ties differ from RNE by 1 ulp
// only at exact halfway points - negligible for this workload.
__device__ __forceinline__ unsigned bfpk2(float a, float b) {
    return __builtin_amdgcn_perm(__float_as_uint(b) + 0x8000u,
                                 __float_as_uint(a) + 0x8000u,
                                 0x07060302u);
}

__global__ void zero_accum_kernel(float* __restrict__ p) {
    p[blockIdx.x * 256 + threadIdx.x] = 0.0f;   // grid 512 x 256 = 131072 floats
}

// grid dim3(64, 4): blockIdx.x = K-split s, blockIdx.y = ph (pose*2 + y-half)
template <bool STORE>
__global__ __launch_bounds__(1024) void render_kernel(
    const float* __restrict__ gpos, const float* __restrict__ gcol,
    const float* __restrict__ gopa, const float* __restrict__ gscl,
    const float* __restrict__ qvec, const float* __restrict__ tvec,
    float* __restrict__ accum,                 // ATOMIC path: [2][128 y][512 n] fp32
    float* __restrict__ pbuf)                  // STORE path: [4 ph][64 s][64 y][512 n] fp32
{
    __shared__ ushort A_lds[64][APAD];               // fy,  [yl][kc]      9 KB
    __shared__ ushort B_lds[512][APAD];              // B^T, [n][kc]      72 KB
    __shared__ float u_s[SLAB], v_s[SLAB], ke_s[SLAB];
    __shared__ float wc_s[4][SLAB];                  // op*{r,g,b,1}

    const int split = blockIdx.x;                    // 0..63
    const int ph    = blockIdx.y;                    // 0..3
    const int pose  = ph >> 1;
    const int half  = ph & 1;                        // y in [half*64, half*64+64)
    const int tid   = threadIdx.x;                   // 0..1023

    // ---- camera: quaternion -> R (all threads, registers) ----
    float q0 = qvec[pose*4+0], q1 = qvec[pose*4+1], q2 = qvec[pose*4+2], q3 = qvec[pose*4+3];
    float rn = rsqrtf(q0*q0 + q1*q1 + q2*q2 + q3*q3);
    float qw = q0*rn, qx = q1*rn, qy = q2*rn, qz = q3*rn;
    float r00 = 1.0f-2.0f*(qy*qy+qz*qz), r01 = 2.0f*(qx*qy-qz*qw), r02 = 2.0f*(qx*qz+qy*qw);
    float r10 = 2.0f*(qx*qy+qz*qw), r11 = 1.0f-2.0f*(qx*qx+qz*qz), r12 = 2.0f*(qy*qz-qx*qw);
    float r20 = 2.0f*(qx*qz-qy*qw), r21 = 2.0f*(qy*qz+qx*qw), r22 = 1.0f-2.0f*(qx*qx+qy*qy);
    float tx = tvec[pose*3+0], ty = tvec[pose*3+1], tz = tvec[pose*3+2];

    // ---- per-slab gaussian params, staged once (1 gaussian / thread) ----
    {
        int g = split*SLAB + tid;
        float p0 = gpos[g*3+0], p1 = gpos[g*3+1], p2 = gpos[g*3+2];
        float cxm = r00*p0 + r01*p1 + r02*p2 + tx;
        float cym = r10*p0 + r11*p1 + r12*p2 + ty;
        float czm = r20*p0 + r21*p1 + r22*p2 + tz;
        float iz  = 1.0f / czm;
        u_s[tid] = cxm*iz*FX_C + CX_C;
        v_s[tid] = cym*iz*FY_C + CY_C;
        float s  = gscl[g];
        ke_s[tid] = NEG_HALF_LOG2E / (s*s);
        float og = gopa[g];
        wc_s[0][tid] = og * gcol[g*3+0];
        wc_s[1][tid] = og * gcol[g*3+1];
        wc_s[2][tid] = og * gcol[g*3+2];
        wc_s[3][tid] = og;
    }
    __syncthreads();

    // A staging map: every thread does 4 fy values. rowA 0..63, qg in {0,4,..,60}
    const int rowA = tid >> 4;
    const int qg   = (tid & 15) << 2;
    const float cjA = (float)(half*64 + rowA);
    // B staging map: every thread does 8 fx values. row_x 0..127, oct in {0,8,..,56}
    const int row_x = tid >> 3;
    const int oct   = (tid & 7) << 3;
    const float cjB = (float)row_x;

    const int lane = tid & 63;
    const int wave = tid >> 6;           // 0..15
    const int wy   = wave >> 3;          // y band: [wy*32, wy*32+32) local
    const int wn   = wave & 7;           // n band: [wn*64, wn*64+64)

    f32x4 acc0[4] = {};                  // rows wy*32 + (lane>>4)*4 + r
    f32x4 acc1[4] = {};                  // +16

    for (int ch = 0; ch < NCHUNK; ++ch) {
        // ---- stage fy -> A_lds[rowA][qg..qg+3] ----
        {
            const int gb = (ch << 6) + qg;
            const float4 kv = *(const float4*)&ke_s[gb];
            const float4 vv = *(const float4*)&v_s[gb];
            float d, f0, f1, f2, f3;
            d = cjA - vv.x; f0 = EXP2(kv.x*d*d);
            d = cjA - vv.y; f1 = EXP2(kv.y*d*d);
            d = cjA - vv.z; f2 = EXP2(kv.z*d*d);
            d = cjA - vv.w; f3 = EXP2(kv.w*d*d);
            uint2 pk;
            pk.x = bfpk2(f0, f1); pk.y = bfpk2(f2, f3);
            *(uint2*)&A_lds[rowA][qg] = pk;
        }
        // ---- stage fx, channel-weighted -> B_lds[c*128 + row_x][oct..] ----
        {
            const int gb = (ch << 6) + oct;
            const float4 ka = *(const float4*)&ke_s[gb];
            const float4 kb = *(const float4*)&ke_s[gb+4];
            const float4 ua = *(const float4*)&u_s[gb];
            const float4 ub = *(const float4*)&u_s[gb+4];
            float d, x0,x1,x2,x3,x4,x5,x6,x7;
            d = cjB - ua.x; x0 = EXP2(ka.x*d*d);
            d = cjB - ua.y; x1 = EXP2(ka.y*d*d);
            d = cjB - ua.z; x2 = EXP2(ka.z*d*d);
            d = cjB - ua.w; x3 = EXP2(ka.w*d*d);
            d = cjB - ub.x; x4 = EXP2(kb.x*d*d);
            d = cjB - ub.y; x5 = EXP2(kb.y*d*d);
            d = cjB - ub.z; x6 = EXP2(kb.z*d*d);
            d = cjB - ub.w; x7 = EXP2(kb.w*d*d);
            #pragma unroll
            for (int c = 0; c < 4; ++c) {
                const float4 wa = *(const float4*)&wc_s[c][gb];
                const float4 wb = *(const float4*)&wc_s[c][gb+4];
                uint4 pk;
                pk.x = bfpk2(x0*wa.x, x1*wa.y);
                pk.y = bfpk2(x2*wa.z, x3*wa.w);
                pk.z = bfpk2(x4*wb.x, x5*wb.y);
                pk.w = bfpk2(x6*wb.z, x7*wb.w);
                *(uint4*)&B_lds[(c << 7) + row_x][oct] = pk;
            }
        }
        __syncthreads();
        // ---- MFMA over this chunk: K=64 -> 2 k-steps of 32 ----
        {
            const int kq = (lane >> 4) << 3;           // verified: k = quad*8 + j
            #pragma unroll
            for (int ks = 0; ks < 2; ++ks) {
                const int ko = ks*32 + kq;
                short8 a0 = *(const short8*)&A_lds[wy*32      + (lane & 15)][ko];
                short8 a1 = *(const short8*)&A_lds[wy*32 + 16 + (lane & 15)][ko];
                #pragma unroll
                for (int ni = 0; ni < 4; ++ni) {
                    short8 bf = *(const short8*)&B_lds[wn*64 + ni*16 + (lane & 15)][ko];
                    acc0[ni] = __builtin_amdgcn_mfma_f32_16x16x32_bf16(a0, bf, acc0[ni], 0, 0, 0);
                    acc1[ni] = __builtin_amdgcn_mfma_f32_16x16x32_bf16(a1, bf, acc1[ni], 0, 0, 0);
                }
            }
        }
        __syncthreads();
    }

    // ---- epilogue ----
    // C/D layout (verified): col(n) = lane&15, row(m) = (lane>>4)*4 + reg
    const int m_base = wy*32 + ((lane >> 4) << 2);    // local y in [0,64)
    const int n_base = wn*64 + (lane & 15);
    if (STORE) {
        // contention-free fp32 partial store: [ph][split][yl][n]
        float* bp = pbuf + ((size_t)(ph*KSPLIT + split) * 64 + m_base) * 512 + n_base;
        #pragma unroll
        for (int ni = 0; ni < 4; ++ni) {
            #pragma unroll
            for (int r = 0; r < 4; ++r) {
                bp[r*512        + ni*16] = acc0[ni][r];
                bp[(16 + r)*512 + ni*16] = acc1[ni][r];
            }
        }
    } else {
        float* bp = accum + ((size_t)(pose*H_IMG + half*64 + m_base) * 512 + n_base);
        #pragma unroll
        for (int ni = 0; ni < 4; ++ni) {
            #pragma unroll
            for (int r = 0; r < 4; ++r) {
                atomicAdd(bp + r*512        + ni*16, acc0[ni][r]);
                atomicAdd(bp + (16 + r)*512 + ni*16, acc1[ni][r]);
            }
        }
    }
}

// STORE path: sum the 64 split partials, normalize, emit tiled output layout.
// grid 256 = (pose, y); 1024 threads = (s-half sg, n 0..511).
__global__ __launch_bounds__(1024) void reduce_norm_kernel(
    const float* __restrict__ pbuf, float* __restrict__ out)
{
    __shared__ float red[2][512];
    const int b  = blockIdx.x;
    const int p  = b >> 7;
    const int y  = b & 127;
    const int ph = p*2 + (y >> 6);
    const int yl = y & 63;
    const int t  = threadIdx.x;
    const int sg = t >> 9;               // 0/1: splits [sg*32, sg*32+32)
    const int n  = t & 511;

    const float* base = pbuf + ((size_t)(ph*KSPLIT + sg*32) * 64 + yl) * 512 + n;
    float s = 0.0f;
    #pragma unroll 8
    for (int i = 0; i < 32; ++i) s += base[(size_t)i * 32768];
    red[sg][n] = s;
    __syncthreads();

    if (t < 384) {
        const int c = t >> 7, x = t & 127;
        float den = red[0][384 + x] + red[1][384 + x];
        float num = red[0][t]       + red[1][t];
        float inv = 1.0f / (den + EPS_TOT);
        // output: [pose*16 + tile][3][32][32], tile = y>>3, q = (y&7)*128 + x
        int tt = y >> 3;
        int q  = ((y & 7) << 7) + x;
        out[(size_t)((p*16 + tt)*3 + c) * 1024 + q] = num * inv;
    }
}

// ATOMIC fallback: img = num/(den+eps), tiled output layout.
__global__ void normalize_kernel(const float* __restrict__ acc, float* __restrict__ out) {
    int idx = blockIdx.x * 256 + threadIdx.x;   // 0..32767 : (pose, y, x)
    int x = idx & 127;
    int y = (idx >> 7) & 127;
    int p = idx >> 14;
    const float* base = acc + (size_t)(p*128 + y) * 512;
    float inv = 1.0f / (base[384 + x] + EPS_TOT);
    int t = y >> 3;
    int q = ((y & 7) << 7) + x;
    float* ob = out + (size_t)((p*16 + t)*3) * 1024 + q;
    ob[0]    = base[x]       * inv;
    ob[1024] = base[128 + x] * inv;
    ob[2048] = base[256 + x] * inv;
}

extern "C" void kernel_launch(void* const* d_in, const int* in_sizes, int n_in,
                              void* d_out, int out_size, void* d_ws, size_t ws_size,
                              hipStream_t stream) {
    const float* gpos = (const float*)d_in[0];   // [65536,3]
    const float* gcol = (const float*)d_in[1];   // [65536,3]
    const float* gopa = (const float*)d_in[2];   // [65536,1]
    const float* gscl = (const float*)d_in[3];   // [65536,1]
    const float* qv   = (const float*)d_in[4];   // [2,4]
    const float* tv   = (const float*)d_in[5];   // [2,3]
    float* out = (float*)d_out;                  // [32,3,32,32] fp32

    // fp32 partials: 4 ph * 64 splits * 64 y * 512 n * 4B = 33,554,432 B
    const size_t need = (size_t)4 * KSPLIT * 64 * 512 * sizeof(float);

    if (ws_size >= need) {
        float* pbuf = (float*)d_ws;
        render_kernel<true><<<dim3(KSPLIT, 4), dim3(1024), 0, stream>>>(
            gpos, gcol, gopa, gscl, qv, tv, nullptr, pbuf);
        reduce_norm_kernel<<<dim3(256), dim3(1024), 0, stream>>>(pbuf, out);
    } else {
        float* acc = (float*)d_ws;               // 512 KB fp32 accumulator
        zero_accum_kernel<<<dim3(512), dim3(256), 0, stream>>>(acc);
        render_kernel<false><<<dim3(KSPLIT, 4), dim3(1024), 0, stream>>>(
            gpos, gcol, gopa, gscl, qv, tv, acc, nullptr);
        normalize_kernel<<<dim3(128), dim3(256), 0, stream>>>(acc, out);
    }
}

// Round 4
// 114.923 us; speedup vs baseline: 1.3056x; 1.0235x over previous
//
#include <hip/hip_runtime.h>

// Differentiable gaussian renderer, separable-splat formulation.
//
//   w(px,py) = op * exp(-0.5*((px-u)^2+(py-v)^2)/var)
//            = [exp2(ke*(py-v)^2)] * [exp2(ke*(px-u)^2)],  ke = -0.5*log2(e)/var
//
// => per pose: C[y][n] = sum_g A[y][g] * B[g][n],  n = c*128+x
//    A[y][g]       = fy_g(y)                    (shared across channels)
//    B[g][c*128+x] = (op*color_c)_g * fx_g(x)   (c=3: color=1 -> denominator)
//
// R3 -> R4: render was LDS-pipe-bound (~0.5 MB LDS traffic/chunk/CU ~= 39us).
//  * [64y x 64n] wave tiles + in-block split-K (waves 0-7: k 0..31, 8-15:
//    k 32..63 of each chunk; one K=32 MFMA step; 2-round LDS acc merge):
//    fragment reads 192 -> 128 KB/chunk.
//  * staging role split (512 B-threads @ 4g x 4x, 512 A-threads @ 4g x 2y):
//    param reads 224 -> 64 KB/chunk.
// Same math/rounding as R3 (absmax anchor 0.0078).

#define H_IMG 128
#define W_IMG 128
#define FX_C 120.0f
#define FY_C 120.0f
#define CX_C 64.0f
#define CY_C 64.0f
#define NG 65536
#define SLAB 1024         // gaussians per block
#define KSPLIT 64         // NG / SLAB
#define NCHUNK 16         // SLAB / 64
#define APAD 72           // 64 + 8 bf16 pad: row stride 144B (16B aligned)
#define NEG_HALF_LOG2E -0.72134752044448170f
#define EPS_TOT 1.6e-7f   // n_chunks(16) * 1e-8

#if __has_builtin(__builtin_amdgcn_exp2f)
#define EXP2(x) __builtin_amdgcn_exp2f(x)
#else
#define EXP2(x) exp2f(x)
#endif

typedef __attribute__((ext_vector_type(8))) short short8;   // 8 bf16 = 4 VGPRs
typedef __attribute__((ext_vector_type(4))) float f32x4;    // MFMA acc

// pack two f32 -> two bf16 (round-half-up) in 3 VALU ops via v_perm_b32.
// result low16 = bf16(a), high16 = bf16(b).
__device__ __forceinline__ unsigned bfpk2(float a, float b) {
    return __builtin_amdgcn_perm(__float_as_uint(b) + 0x8000u,
                                 __float_as_uint(a) + 0x8000u,
                                 0x07060302u);
}

__global__ void zero_accum_kernel(float* __restrict__ p) {
    p[blockIdx.x * 256 + threadIdx.x] = 0.0f;   // grid 512 x 256 = 131072 floats
}

// grid dim3(64, 4): blockIdx.x = K-split s, blockIdx.y = ph (pose*2 + y-half)
template <bool STORE>
__global__ __launch_bounds__(1024) void render_kernel(
    const float* __restrict__ gpos, const float* __restrict__ gcol,
    const float* __restrict__ gopa, const float* __restrict__ gscl,
    const float* __restrict__ qvec, const float* __restrict__ tvec,
    float* __restrict__ accum,                 // ATOMIC path: [2][128 y][512 n] fp32
    float* __restrict__ pbuf)                  // STORE path: [4 ph][64 s][64 y][512 n] fp32
{
    __shared__ ushort A_lds[64][APAD];               // fy,  [yl][kc]      9 KB
    __shared__ ushort B_lds[512][APAD];              // B^T, [n][kc]      72 KB (reused as merge scratch)
    __shared__ float u_s[SLAB], v_s[SLAB], ke_s[SLAB];
    __shared__ float wc_s[4][SLAB];                  // op*{r,g,b,1}

    const int split = blockIdx.x;                    // 0..63
    const int ph    = blockIdx.y;                    // 0..3
    const int pose  = ph >> 1;
    const int half  = ph & 1;                        // y in [half*64, half*64+64)
    const int tid   = threadIdx.x;                   // 0..1023

    // ---- camera: quaternion -> R ----
    float q0 = qvec[pose*4+0], q1 = qvec[pose*4+1], q2 = qvec[pose*4+2], q3 = qvec[pose*4+3];
    float rn = rsqrtf(q0*q0 + q1*q1 + q2*q2 + q3*q3);
    float qw = q0*rn, qx = q1*rn, qy = q2*rn, qz = q3*rn;
    float r00 = 1.0f-2.0f*(qy*qy+qz*qz), r01 = 2.0f*(qx*qy-qz*qw), r02 = 2.0f*(qx*qz+qy*qw);
    float r10 = 2.0f*(qx*qy+qz*qw), r11 = 1.0f-2.0f*(qx*qx+qz*qz), r12 = 2.0f*(qy*qz-qx*qw);
    float r20 = 2.0f*(qx*qz-qy*qw), r21 = 2.0f*(qy*qz+qx*qw), r22 = 1.0f-2.0f*(qx*qx+qy*qy);
    float tx = tvec[pose*3+0], ty = tvec[pose*3+1], tz = tvec[pose*3+2];

    // ---- per-slab gaussian params, staged once (1 gaussian / thread) ----
    {
        int g = split*SLAB + tid;
        float p0 = gpos[g*3+0], p1 = gpos[g*3+1], p2 = gpos[g*3+2];
        float cxm = r00*p0 + r01*p1 + r02*p2 + tx;
        float cym = r10*p0 + r11*p1 + r12*p2 + ty;
        float czm = r20*p0 + r21*p1 + r22*p2 + tz;
        float iz  = 1.0f / czm;
        u_s[tid] = cxm*iz*FX_C + CX_C;
        v_s[tid] = cym*iz*FY_C + CY_C;
        float s  = gscl[g];
        ke_s[tid] = NEG_HALF_LOG2E / (s*s);
        float og = gopa[g];
        wc_s[0][tid] = og * gcol[g*3+0];
        wc_s[1][tid] = og * gcol[g*3+1];
        wc_s[2][tid] = og * gcol[g*3+2];
        wc_s[3][tid] = og;
    }
    __syncthreads();

    const int lane = tid & 63;
    const int wave = tid >> 6;            // 0..15
    const int kset = wave >> 3;           // 0: k 0..31 of chunk, 1: k 32..63
    const int wn8  = wave & 7;            // n band: [wn8*64, wn8*64+64)

    // staging roles: threads 0..511 stage B (4g x 4x), 512..1023 stage A (4g x 2y)
    const bool isB = (tid < 512);
    const int st   = isB ? tid : (tid - 512);
    const int g4   = (st & 15) << 2;      // 0,4,..,60
    const int grp  = st >> 4;             // 0..31

    // MFMA frag addressing (verified layouts)
    const int arow = lane & 15;
    const int kcol = kset*32 + ((lane >> 4) << 3);   // k = kset*32 + quad*8 + j

    f32x4 acc[4][4] = {};                 // [mt][nt]: m = mt*16+quad*4+r, n = wn8*64+nt*16+(lane&15)

    for (int ch = 0; ch < NCHUNK; ++ch) {
        const int gb = (ch << 6) + g4;
        if (isB) {
            // ---- stage fx, channel-weighted -> B_lds[c*128 + x][g4..g4+3], x = grp*4+xi ----
            const float4 kv = *(const float4*)&ke_s[gb];
            const float4 uv = *(const float4*)&u_s[gb];
            float e[4][4];
            #pragma unroll
            for (int xi = 0; xi < 4; ++xi) {
                const float xf = (float)(grp*4 + xi);
                float d;
                d = xf - uv.x; e[xi][0] = EXP2(kv.x*d*d);
                d = xf - uv.y; e[xi][1] = EXP2(kv.y*d*d);
                d = xf - uv.z; e[xi][2] = EXP2(kv.z*d*d);
                d = xf - uv.w; e[xi][3] = EXP2(kv.w*d*d);
            }
            #pragma unroll
            for (int c = 0; c < 4; ++c) {
                const float4 wv = *(const float4*)&wc_s[c][gb];
                #pragma unroll
                for (int xi = 0; xi < 4; ++xi) {
                    uint2 pk;
                    pk.x = bfpk2(e[xi][0]*wv.x, e[xi][1]*wv.y);
                    pk.y = bfpk2(e[xi][2]*wv.z, e[xi][3]*wv.w);
                    *(uint2*)&B_lds[(c << 7) + grp*4 + xi][g4] = pk;
                }
            }
        } else {
            // ---- stage fy -> A_lds[yl][g4..g4+3], yl = grp*2+yi ----
            const float4 kv = *(const float4*)&ke_s[gb];
            const float4 vv = *(const float4*)&v_s[gb];
            #pragma unroll
            for (int yi = 0; yi < 2; ++yi) {
                const float yf = (float)(half*64 + grp*2 + yi);
                float d, f0, f1, f2, f3;
                d = yf - vv.x; f0 = EXP2(kv.x*d*d);
                d = yf - vv.y; f1 = EXP2(kv.y*d*d);
                d = yf - vv.z; f2 = EXP2(kv.z*d*d);
                d = yf - vv.w; f3 = EXP2(kv.w*d*d);
                uint2 pk;
                pk.x = bfpk2(f0, f1); pk.y = bfpk2(f2, f3);
                *(uint2*)&A_lds[grp*2 + yi][g4] = pk;
            }
        }
        __syncthreads();
        // ---- MFMA: single K=32 step per wave (split-K across wave sets) ----
        {
            short8 a[4], b[4];
            #pragma unroll
            for (int mt = 0; mt < 4; ++mt)
                a[mt] = *(const short8*)&A_lds[mt*16 + arow][kcol];
            #pragma unroll
            for (int nt = 0; nt < 4; ++nt)
                b[nt] = *(const short8*)&B_lds[wn8*64 + nt*16 + arow][kcol];
            #pragma unroll
            for (int mt = 0; mt < 4; ++mt)
                #pragma unroll
                for (int nt = 0; nt < 4; ++nt)
                    acc[mt][nt] = __builtin_amdgcn_mfma_f32_16x16x32_bf16(a[mt], b[nt], acc[mt][nt], 0, 0, 0);
        }
        __syncthreads();
    }

    // ---- split-K merge: kset1 -> kset0 via B_lds scratch (64 KB/round, 2 rounds) ----
    f32x4* scr = (f32x4*)&B_lds[0][0];
    #pragma unroll
    for (int r = 0; r < 2; ++r) {
        if (kset == 1) {
            #pragma unroll
            for (int m2 = 0; m2 < 2; ++m2)
                #pragma unroll
                for (int nt = 0; nt < 4; ++nt)
                    scr[(((wn8*2 + m2)*4 + nt) << 6) + lane] = acc[r*2 + m2][nt];
        }
        __syncthreads();
        if (kset == 0) {
            #pragma unroll
            for (int m2 = 0; m2 < 2; ++m2)
                #pragma unroll
                for (int nt = 0; nt < 4; ++nt)
                    acc[r*2 + m2][nt] += scr[(((wn8*2 + m2)*4 + nt) << 6) + lane];
        }
        __syncthreads();
    }

    // ---- epilogue (kset0 waves only): [64y x 64n] per wave ----
    if (kset == 0) {
        const int m0 = (lane >> 4) << 2;          // 0,4,8,12
        const int n0 = wn8*64 + (lane & 15);
        if (STORE) {
            float* bp = pbuf + ((size_t)(ph*KSPLIT + split) * 64) * 512 + n0;
            #pragma unroll
            for (int mt = 0; mt < 4; ++mt)
                #pragma unroll
                for (int nt = 0; nt < 4; ++nt)
                    #pragma unroll
                    for (int r = 0; r < 4; ++r)
                        bp[(size_t)(mt*16 + m0 + r)*512 + nt*16] = acc[mt][nt][r];
        } else {
            float* bp = accum + ((size_t)(pose*H_IMG + half*64) * 512) + n0;
            #pragma unroll
            for (int mt = 0; mt < 4; ++mt)
                #pragma unroll
                for (int nt = 0; nt < 4; ++nt)
                    #pragma unroll
                    for (int r = 0; r < 4; ++r)
                        atomicAdd(bp + (size_t)(mt*16 + m0 + r)*512 + nt*16, acc[mt][nt][r]);
        }
    }
}

// STORE path: sum the 64 split partials, normalize, emit tiled output layout.
// grid 256 = (pose, y); 1024 threads = (s-half sg, n 0..511).
__global__ __launch_bounds__(1024) void reduce_norm_kernel(
    const float* __restrict__ pbuf, float* __restrict__ out)
{
    __shared__ float red[2][512];
    const int b  = blockIdx.x;
    const int p  = b >> 7;
    const int y  = b & 127;
    const int ph = p*2 + (y >> 6);
    const int yl = y & 63;
    const int t  = threadIdx.x;
    const int sg = t >> 9;               // 0/1: splits [sg*32, sg*32+32)
    const int n  = t & 511;

    const float* base = pbuf + ((size_t)(ph*KSPLIT + sg*32) * 64 + yl) * 512 + n;
    float s = 0.0f;
    #pragma unroll 8
    for (int i = 0; i < 32; ++i) s += base[(size_t)i * 32768];
    red[sg][n] = s;
    __syncthreads();

    if (t < 384) {
        const int c = t >> 7, x = t & 127;
        float den = red[0][384 + x] + red[1][384 + x];
        float num = red[0][t]       + red[1][t];
        float inv = 1.0f / (den + EPS_TOT);
        // output: [pose*16 + tile][3][32][32], tile = y>>3, q = (y&7)*128 + x
        int tt = y >> 3;
        int q  = ((y & 7) << 7) + x;
        out[(size_t)((p*16 + tt)*3 + c) * 1024 + q] = num * inv;
    }
}

// ATOMIC fallback: img = num/(den+eps), tiled output layout.
__global__ void normalize_kernel(const float* __restrict__ acc, float* __restrict__ out) {
    int idx = blockIdx.x * 256 + threadIdx.x;   // 0..32767 : (pose, y, x)
    int x = idx & 127;
    int y = (idx >> 7) & 127;
    int p = idx >> 14;
    const float* base = acc + (size_t)(p*128 + y) * 512;
    float inv = 1.0f / (base[384 + x] + EPS_TOT);
    int t = y >> 3;
    int q = ((y & 7) << 7) + x;
    float* ob = out + (size_t)((p*16 + t)*3) * 1024 + q;
    ob[0]    = base[x]       * inv;
    ob[1024] = base[128 + x] * inv;
    ob[2048] = base[256 + x] * inv;
}

extern "C" void kernel_launch(void* const* d_in, const int* in_sizes, int n_in,
                              void* d_out, int out_size, void* d_ws, size_t ws_size,
                              hipStream_t stream) {
    const float* gpos = (const float*)d_in[0];   // [65536,3]
    const float* gcol = (const float*)d_in[1];   // [65536,3]
    const float* gopa = (const float*)d_in[2];   // [65536,1]
    const float* gscl = (const float*)d_in[3];   // [65536,1]
    const float* qv   = (const float*)d_in[4];   // [2,4]
    const float* tv   = (const float*)d_in[5];   // [2,3]
    float* out = (float*)d_out;                  // [32,3,32,32] fp32

    // fp32 partials: 4 ph * 64 splits * 64 y * 512 n * 4B = 33,554,432 B
    const size_t need = (size_t)4 * KSPLIT * 64 * 512 * sizeof(float);

    if (ws_size >= need) {
        float* pbuf = (float*)d_ws;
        render_kernel<true><<<dim3(KSPLIT, 4), dim3(1024), 0, stream>>>(
            gpos, gcol, gopa, gscl, qv, tv, nullptr, pbuf);
        reduce_norm_kernel<<<dim3(256), dim3(1024), 0, stream>>>(pbuf, out);
    } else {
        float* acc = (float*)d_ws;               // 512 KB fp32 accumulator
        zero_accum_kernel<<<dim3(512), dim3(256), 0, stream>>>(acc);
        render_kernel<false><<<dim3(KSPLIT, 4), dim3(1024), 0, stream>>>(
            gpos, gcol, gopa, gscl, qv, tv, acc, nullptr);
        normalize_kernel<<<dim3(128), dim3(256), 0, stream>>>(acc, out);
    }
}